// Round 1
// baseline (237.440 us; speedup 1.0000x reference)
//
#include <hip/hip_runtime.h>
#include <hip/hip_bf16.h>
#include <stdint.h>

// Problem constants (from reference): B=16384, F=32, D=64, H=2*D=128.
#define B_SZ 16384
#define F_SZ 32
#define D_SZ 64
#define H_SZ 128

typedef __attribute__((ext_vector_type(8))) short  short8;   // 8 x bf16 MFMA frag
typedef __attribute__((ext_vector_type(4))) float  float4v;  // MFMA acc
typedef __attribute__((ext_vector_type(4))) unsigned int uint4v;

// round-half-up f32->bf16, pack (lo -> bits[15:0], hi -> bits[31:16])
__device__ __forceinline__ unsigned int pkbf(float lo, float hi) {
  unsigned int ulo = __builtin_bit_cast(unsigned int, lo) + 0x8000u;
  unsigned int uhi = __builtin_bit_cast(unsigned int, hi) + 0x8000u;
  // v_perm_b32: byte sel indexes {S1 bytes 0-3, S0 bytes 4-7}
  return __builtin_amdgcn_perm(uhi, ulo, 0x07060302u);
}

// Kernel 1: W1 [F][D][H] f32 -> w1t [F][H][D] bf16 (transposed so a lane can
// read 8 consecutive d per h, i.e. MFMA A-fragment order). Also pack
// {b1,w2} per h as one u32 (b1 in hi16, w2 in lo16).
__global__ __launch_bounds__(256) void ContMlp_prep(
    const float* __restrict__ W1, const float* __restrict__ b1,
    const float* __restrict__ W2, unsigned short* __restrict__ w1t,
    unsigned int* __restrict__ bw) {
  const int f = blockIdx.x;
  const int t = threadIdx.x;
  __shared__ float lds[D_SZ][H_SZ + 1];  // +1 pad: conflict-free transpose
  const float* w1f = W1 + (size_t)f * (D_SZ * H_SZ);
#pragma unroll
  for (int i = 0; i < 32; ++i) {       // coalesced read, [d][h] stage
    int e = t + 256 * i;
    lds[e >> 7][e & 127] = w1f[e];
  }
  __syncthreads();
  unsigned short* o = w1t + (size_t)f * (H_SZ * D_SZ);
#pragma unroll
  for (int i = 0; i < 32; ++i) {       // coalesced bf16 write, [h][d]
    int e = t + 256 * i;
    int h = e >> 6, d = e & 63;
    unsigned int u = __builtin_bit_cast(unsigned int, lds[d][h]) + 0x8000u;
    o[e] = (unsigned short)(u >> 16);
  }
  if (t < H_SZ) {
    unsigned int ub = __builtin_bit_cast(unsigned int, b1[f * H_SZ + t]) + 0x8000u;
    unsigned int uw = __builtin_bit_cast(unsigned int, W2[f * H_SZ + t]) + 0x8000u;
    bw[f * H_SZ + t] = (ub & 0xFFFF0000u) | (uw >> 16);
  }
}

// Kernel 2: grid = (B/256) tiles x 32 features. Block = 4 waves; each wave
// does 4 subtiles of 16 batch rows. Per subtile: C[h][b] (16x16) tiles t=0..7
// over H via mfma_f32_16x16x32_bf16 with K=D=64 (2 k-steps).
//   A frag (W1T): lane h=(l&15)+16t, d = ks*32 + (l>>4)*8 + j   (regs, per block)
//   B frag (r_):  lane b=b0+(l&15),  d = ks*32 + (l>>4)*8 + j   (global f32 -> cvt)
//   C layout:     col(b)=l&15, row(h-in-tile)=(l>>4)*4+reg
// Epilogue: y[b] = relu(sum_h relu(acc+b1)*w2 + b2); reduce over quads via
// shfl_xor 16/32; lanes 0-15 store float2 {X, y}.
__global__ __launch_bounds__(256, 3) void ContMlp_main(
    const float* __restrict__ X, const float* __restrict__ r_,
    const unsigned short* __restrict__ w1t, const unsigned int* __restrict__ bw,
    const float* __restrict__ b2, float* __restrict__ out) {
  const int f    = blockIdx.x & 31;
  const int tile = blockIdx.x >> 5;
  const int w    = threadIdx.x >> 6;
  const int l    = threadIdx.x & 63;
  const int col  = l & 15;
  const int quad = l >> 4;

  // --- per-block register-resident weights ---
  const unsigned short* w1f = w1t + (size_t)f * (H_SZ * D_SZ);
  short8 afrag[8][2];
#pragma unroll
  for (int t = 0; t < 8; ++t)
#pragma unroll
    for (int ks = 0; ks < 2; ++ks) {
      const uint4v* p = (const uint4v*)(w1f + (col + 16 * t) * D_SZ + ks * 32 + quad * 8);
      afrag[t][ks] = __builtin_bit_cast(short8, *p);
    }
  uint4v bwreg[8];  // {b1,w2} for h = 16t + quad*4 + r
#pragma unroll
  for (int t = 0; t < 8; ++t)
    bwreg[t] = *(const uint4v*)(bw + f * H_SZ + 16 * t + quad * 4);
  const float b2f = b2[f];

  const int b_wave = tile * 256 + w * 64;
#pragma unroll
  for (int s = 0; s < 4; ++s) {
    const int b0  = b_wave + s * 16;
    const int row = b0 + col;
    const float* rp = r_ + (size_t)row * (F_SZ * D_SZ) + f * D_SZ + quad * 8;
    float4v r0 = *(const float4v*)(rp);
    float4v r1 = *(const float4v*)(rp + 4);
    float4v r2 = *(const float4v*)(rp + 32);
    float4v r3 = *(const float4v*)(rp + 36);

    unsigned int p0 = pkbf(r0.x, r0.y), p1 = pkbf(r0.z, r0.w);
    unsigned int p2 = pkbf(r1.x, r1.y), p3 = pkbf(r1.z, r1.w);
    unsigned int p4 = pkbf(r2.x, r2.y), p5 = pkbf(r2.z, r2.w);
    unsigned int p6 = pkbf(r3.x, r3.y), p7 = pkbf(r3.z, r3.w);
    uint4v bq0 = {p0, p1, p2, p3};
    uint4v bq1 = {p4, p5, p6, p7};
    short8 bfrag0 = __builtin_bit_cast(short8, bq0);
    short8 bfrag1 = __builtin_bit_cast(short8, bq1);

    float4v acc[8];
#pragma unroll
    for (int t = 0; t < 8; ++t) acc[t] = {0.f, 0.f, 0.f, 0.f};
#pragma unroll
    for (int t = 0; t < 8; ++t) {
      acc[t] = __builtin_amdgcn_mfma_f32_16x16x32_bf16(afrag[t][0], bfrag0, acc[t], 0, 0, 0);
      acc[t] = __builtin_amdgcn_mfma_f32_16x16x32_bf16(afrag[t][1], bfrag1, acc[t], 0, 0, 0);
    }

    float ysum = 0.f;
#pragma unroll
    for (int t = 0; t < 8; ++t)
#pragma unroll
      for (int r = 0; r < 4; ++r) {
        unsigned int u = bwreg[t][r];
        float b1v = __builtin_bit_cast(float, u & 0xFFFF0000u);
        float w2v = __builtin_bit_cast(float, u << 16);
        float hv  = fmaxf(acc[t][r] + b1v, 0.f);
        ysum = fmaf(hv, w2v, ysum);
      }
    ysum += __shfl_xor(ysum, 16, 64);
    ysum += __shfl_xor(ysum, 32, 64);
    float y = fmaxf(ysum + b2f, 0.f);

    if (quad == 0) {
      float xv = X[row * F_SZ + f];
      float2 o2 = make_float2(xv, y);
      *(float2*)(out + (size_t)row * (F_SZ * 2) + f * 2) = o2;
    }
  }
}

extern "C" void kernel_launch(void* const* d_in, const int* in_sizes, int n_in,
                              void* d_out, int out_size, void* d_ws, size_t ws_size,
                              hipStream_t stream) {
  const float* X  = (const float*)d_in[0];
  const float* r_ = (const float*)d_in[1];
  const float* W1 = (const float*)d_in[2];
  const float* b1 = (const float*)d_in[3];
  const float* W2 = (const float*)d_in[4];
  const float* b2 = (const float*)d_in[5];
  float* out = (float*)d_out;

  unsigned short* w1t = (unsigned short*)d_ws;                        // 512 KB
  unsigned int*   bw  = (unsigned int*)((char*)d_ws + (size_t)F_SZ * H_SZ * D_SZ * 2);  // 16 KB

  ContMlp_prep<<<F_SZ, 256, 0, stream>>>(W1, b1, W2, w1t, bw);
  ContMlp_main<<<(B_SZ / 256) * F_SZ, 256, 0, stream>>>(X, r_, w1t, bw, b2, out);
}